// Round 9
// baseline (210.579 us; speedup 1.0000x reference)
//
#include <hip/hip_runtime.h>
#include <hip/hip_bf16.h>
#include <hip/hip_fp16.h>

#define N_NODES_C 100000
#define NSCAN     102400      // N padded to 25 * 4096 for the scan
#define SCAN_BS   1024        // threads per scan block (4 elems each -> 4096/block)
#define NB_SCAN   (NSCAN / (SCAN_BS * 4))   // 25 blocks

// ---------------------------------------------------------------------------
// fp16 helpers: h_src stored as packed fp16 (uint = 2 halves)
// ---------------------------------------------------------------------------
union U2H { unsigned u; __half2 h; };

__device__ __forceinline__ __half2 addp(__half2 a, unsigned u)
{
    U2H c; c.u = u;
    return __hadd2(a, c.h);
}

// h_src f32 -> packed fp16 copy (8 floats per thread)
__global__ __launch_bounds__(256) void convert_fp16(
    const float* __restrict__ x, uint4* __restrict__ y, int n8)
{
    int i = blockIdx.x * 256 + threadIdx.x;
    if (i >= n8) return;
    const float4* x4 = reinterpret_cast<const float4*>(x);
    float4 a = x4[i * 2 + 0];
    float4 b = x4[i * 2 + 1];
    U2H c0, c1, c2, c3;
    c0.h = __floats2half2_rn(a.x, a.y);
    c1.h = __floats2half2_rn(a.z, a.w);
    c2.h = __floats2half2_rn(b.x, b.y);
    c3.h = __floats2half2_rn(b.z, b.w);
    uint4 o;
    o.x = c0.u; o.y = c1.u; o.z = c2.u; o.w = c3.u;
    y[i] = o;
}

// ---------------------------------------------------------------------------
// CSR build: histogram(+rank) -> block scan -> scan_add(inline partials) -> fill
// ---------------------------------------------------------------------------
__global__ __launch_bounds__(256) void edge_hist(
    const int* __restrict__ dst, int* __restrict__ counts,
    int* __restrict__ rank, int n_edges)
{
    int i = blockIdx.x * 256 + threadIdx.x;
    int b4 = i * 4;
    if (b4 + 3 < n_edges) {
        int4 d = reinterpret_cast<const int4*>(dst)[i];
        int4 rk;
        rk.x = atomicAdd(&counts[d.x], 1);
        rk.y = atomicAdd(&counts[d.y], 1);
        rk.z = atomicAdd(&counts[d.z], 1);
        rk.w = atomicAdd(&counts[d.w], 1);
        reinterpret_cast<int4*>(rank)[i] = rk;
    } else {
        for (int e = b4; e < n_edges; ++e)
            rank[e] = atomicAdd(&counts[dst[e]], 1);
    }
}

__global__ __launch_bounds__(SCAN_BS) void scan_block(
    const int* __restrict__ counts, int* __restrict__ offsets,
    int* __restrict__ partials)
{
    __shared__ int sd[2][SCAN_BS];
    int t = threadIdx.x, b = blockIdx.x;
    int4 c = reinterpret_cast<const int4*>(counts)[b * SCAN_BS + t];
    int tot = c.x + c.y + c.z + c.w;
    sd[0][t] = tot;
    __syncthreads();
    int pin = 0;
    #pragma unroll
    for (int off = 1; off < SCAN_BS; off <<= 1) {
        int v = sd[pin][t];
        if (t >= off) v += sd[pin][t - off];
        sd[pin ^ 1][t] = v;
        pin ^= 1;
        __syncthreads();
    }
    int incl = sd[pin][t];      // inclusive scan of per-thread sums
    int excl = incl - tot;
    int4 o;
    o.x = excl;
    o.y = excl + c.x;
    o.z = excl + c.x + c.y;
    o.w = excl + c.x + c.y + c.z;
    reinterpret_cast<int4*>(offsets)[b * SCAN_BS + t] = o;
    if (t == SCAN_BS - 1) partials[b] = incl;
}

// one block per scan_block tile; thread 0 sums the (<=24) preceding partials
__global__ __launch_bounds__(SCAN_BS) void scan_add(
    int* __restrict__ offsets, const int* __restrict__ partials)
{
    __shared__ int base_s;
    int b = blockIdx.x;
    if (threadIdx.x == 0) {
        int s = 0;
        for (int i = 0; i < b; ++i) s += partials[i];
        base_s = s;
    }
    __syncthreads();
    int i = b * SCAN_BS + threadIdx.x;
    int4 v = reinterpret_cast<int4*>(offsets)[i];
    v.x += base_s; v.y += base_s; v.z += base_s; v.w += base_s;
    reinterpret_cast<int4*>(offsets)[i] = v;
}

__global__ __launch_bounds__(256) void edge_fill(
    const int* __restrict__ src, const int* __restrict__ dst,
    const int* __restrict__ rank, const int* __restrict__ offsets,
    int* __restrict__ edge_src, int n_edges)
{
    int i = blockIdx.x * 256 + threadIdx.x;
    int b4 = i * 4;
    if (b4 + 3 < n_edges) {
        int4 s  = reinterpret_cast<const int4*>(src)[i];
        int4 d  = reinterpret_cast<const int4*>(dst)[i];
        int4 rk = reinterpret_cast<const int4*>(rank)[i];
        edge_src[offsets[d.x] + rk.x] = s.x;
        edge_src[offsets[d.y] + rk.y] = s.y;
        edge_src[offsets[d.z] + rk.z] = s.z;
        edge_src[offsets[d.w] + rk.w] = s.w;
    } else {
        for (int e = b4; e < n_edges; ++e)
            edge_src[offsets[dst[e]] + rank[e]] = src[e];
    }
}

// ---------------------------------------------------------------------------
// Fused gather-mean + GEMM.
// Block: 256 threads, 64 nodes. LDS: X tile only (32KB, swizzled float4).
// Gather: 4 threads/node; per edge each lane loads 2 uint4 fp16 chunks
// (j and j+4, 64B apart); 4-edge unroll -> 8 independent 16B loads in
// flight. Accumulate with packed __hadd2 DIRECTLY on load dests (one
// v_pk_add_f16 per dword, no unpack temporaries) -- R2's dataflow shape,
// which is the only structure the RA has kept concurrent (VGPR=112 there
// vs 40-60 for every bf16-unpack variant, all serialized).
// W streams from global in the GEMM loop (L1-resident, 16-lane dedup).
// ---------------------------------------------------------------------------
__global__ __launch_bounds__(256) void sage_fused(
    const uint4* __restrict__ hsb,      // packed fp16 h_src [N][8] uint4
    const float* __restrict__ h_dst,
    const int*   __restrict__ offsets,
    const int*   __restrict__ edge_src,
    const float* __restrict__ weight,   // [64][128] row-major
    const float* __restrict__ bias,     // [64]
    float*       __restrict__ out,      // [N][64]
    int n_nodes)
{
    __shared__ float4 x4[64 * 32];   // x4[r][c] at r*32 + ((c + r) & 31)

    const int t    = threadIdx.x;
    const int base = blockIdx.x * 64;

    // stage h_dst (cols 0..15): 4 float4 per thread
    #pragma unroll
    for (int q = 0; q < 4; ++q) {
        int idx = t + q * 256;        // 0..1023
        int r   = idx >> 4;
        int k4  = idx & 15;
        int g   = base + r;
        float4 xv = make_float4(0.f, 0.f, 0.f, 0.f);
        if (g < n_nodes)
            xv = reinterpret_cast<const float4*>(h_dst)[(size_t)g * 16 + k4];
        x4[r * 32 + ((k4 + r) & 31)] = xv;
    }

    // gather neighbor mean (cols 16..31): 4 threads/node, 4-edge unroll,
    // 8 concurrent 16B gathers per lane, packed-fp16 accumulate
    {
        const int j = t & 3;          // uint4 chunk pair: j and j+4
        const int r = t >> 2;         // node within tile (0..63)
        const int g = base + r;
        __half2 accA[4], accB[4];     // features [8j..8j+8) and [8(j+4)..)
        const __half2 z = __floats2half2_rn(0.f, 0.f);
        #pragma unroll
        for (int q = 0; q < 4; ++q) { accA[q] = z; accB[q] = z; }
        float invd = 0.f;
        if (g < n_nodes) {
            int e0 = offsets[g];
            int e1 = offsets[g + 1];
            int e  = e0;
            for (; e + 4 <= e1; e += 4) {
                int s0 = edge_src[e + 0];
                int s1 = edge_src[e + 1];
                int s2 = edge_src[e + 2];
                int s3 = edge_src[e + 3];
                // issue all 8 gathers, then consume each dword with one pk_add
                uint4 p0 = hsb[(size_t)s0 * 8 + j];
                uint4 p1 = hsb[(size_t)s1 * 8 + j];
                uint4 p2 = hsb[(size_t)s2 * 8 + j];
                uint4 p3 = hsb[(size_t)s3 * 8 + j];
                uint4 q0 = hsb[(size_t)s0 * 8 + j + 4];
                uint4 q1 = hsb[(size_t)s1 * 8 + j + 4];
                uint4 q2 = hsb[(size_t)s2 * 8 + j + 4];
                uint4 q3 = hsb[(size_t)s3 * 8 + j + 4];
                accA[0] = addp(accA[0], p0.x); accA[1] = addp(accA[1], p0.y);
                accA[2] = addp(accA[2], p0.z); accA[3] = addp(accA[3], p0.w);
                accA[0] = addp(accA[0], p1.x); accA[1] = addp(accA[1], p1.y);
                accA[2] = addp(accA[2], p1.z); accA[3] = addp(accA[3], p1.w);
                accA[0] = addp(accA[0], p2.x); accA[1] = addp(accA[1], p2.y);
                accA[2] = addp(accA[2], p2.z); accA[3] = addp(accA[3], p2.w);
                accA[0] = addp(accA[0], p3.x); accA[1] = addp(accA[1], p3.y);
                accA[2] = addp(accA[2], p3.z); accA[3] = addp(accA[3], p3.w);
                accB[0] = addp(accB[0], q0.x); accB[1] = addp(accB[1], q0.y);
                accB[2] = addp(accB[2], q0.z); accB[3] = addp(accB[3], q0.w);
                accB[0] = addp(accB[0], q1.x); accB[1] = addp(accB[1], q1.y);
                accB[2] = addp(accB[2], q1.z); accB[3] = addp(accB[3], q1.w);
                accB[0] = addp(accB[0], q2.x); accB[1] = addp(accB[1], q2.y);
                accB[2] = addp(accB[2], q2.z); accB[3] = addp(accB[3], q2.w);
                accB[0] = addp(accB[0], q3.x); accB[1] = addp(accB[1], q3.y);
                accB[2] = addp(accB[2], q3.z); accB[3] = addp(accB[3], q3.w);
            }
            for (; e < e1; ++e) {
                int s = edge_src[e];
                uint4 p = hsb[(size_t)s * 8 + j];
                uint4 q = hsb[(size_t)s * 8 + j + 4];
                accA[0] = addp(accA[0], p.x); accA[1] = addp(accA[1], p.y);
                accA[2] = addp(accA[2], p.z); accA[3] = addp(accA[3], p.w);
                accB[0] = addp(accB[0], q.x); accB[1] = addp(accB[1], q.y);
                accB[2] = addp(accB[2], q.z); accB[3] = addp(accB[3], q.w);
            }
            int degv = e1 - e0;
            invd = 1.0f / (float)(degv > 1 ? degv : 1);
        }
        // chunk j  -> float4 cols 16+2j, 17+2j ; chunk j+4 -> 24+2j, 25+2j
        float4 w0 = make_float4(__low2float(accA[0]) * invd,
                                __high2float(accA[0]) * invd,
                                __low2float(accA[1]) * invd,
                                __high2float(accA[1]) * invd);
        float4 w1 = make_float4(__low2float(accA[2]) * invd,
                                __high2float(accA[2]) * invd,
                                __low2float(accA[3]) * invd,
                                __high2float(accA[3]) * invd);
        float4 w2 = make_float4(__low2float(accB[0]) * invd,
                                __high2float(accB[0]) * invd,
                                __low2float(accB[1]) * invd,
                                __high2float(accB[1]) * invd);
        float4 w3 = make_float4(__low2float(accB[2]) * invd,
                                __high2float(accB[2]) * invd,
                                __low2float(accB[3]) * invd,
                                __high2float(accB[3]) * invd);
        x4[r * 32 + (((16 + 2 * j) + r) & 31)] = w0;
        x4[r * 32 + (((17 + 2 * j) + r) & 31)] = w1;
        x4[r * 32 + (((24 + 2 * j) + r) & 31)] = w2;
        x4[r * 32 + (((25 + 2 * j) + r) & 31)] = w3;
    }
    __syncthreads();

    // GEMM: thread tile = 4 nodes x 4 outs; W streamed from global (L1)
    const int m  = t & 15;    // out-group: o0 = 4m
    const int r0 = t >> 4;    // node base: rows r0 + 16*i
    const int o0 = m * 4;

    const float4* w4g = reinterpret_cast<const float4*>(weight);
    float4 bv = reinterpret_cast<const float4*>(bias)[m];

    float acc[4][4];
    #pragma unroll
    for (int i = 0; i < 4; ++i) {
        acc[i][0] = bv.x; acc[i][1] = bv.y; acc[i][2] = bv.z; acc[i][3] = bv.w;
    }

    #pragma unroll 4
    for (int k4 = 0; k4 < 32; ++k4) {
        float4 wv[4];
        #pragma unroll
        for (int jj = 0; jj < 4; ++jj)
            wv[jj] = w4g[(o0 + jj) * 32 + k4];
        #pragma unroll
        for (int i = 0; i < 4; ++i) {
            int r = r0 + 16 * i;
            float4 xv = x4[r * 32 + ((k4 + r) & 31)];
            #pragma unroll
            for (int jj = 0; jj < 4; ++jj) {
                acc[i][jj] += xv.x * wv[jj].x + xv.y * wv[jj].y
                            + xv.z * wv[jj].z + xv.w * wv[jj].w;
            }
        }
    }

    #pragma unroll
    for (int i = 0; i < 4; ++i) {
        int g = base + r0 + 16 * i;
        if (g < n_nodes) {
            float4 ov = make_float4(acc[i][0], acc[i][1], acc[i][2], acc[i][3]);
            reinterpret_cast<float4*>(out)[(size_t)g * 16 + m] = ov;
        }
    }
}

// ---------------------------------------------------------------------------
extern "C" void kernel_launch(void* const* d_in, const int* in_sizes, int n_in,
                              void* d_out, int out_size, void* d_ws, size_t ws_size,
                              hipStream_t stream)
{
    const float* h_src  = (const float*)d_in[0];
    const float* h_dst  = (const float*)d_in[1];
    const int*   src    = (const int*)d_in[2];
    const int*   dst    = (const int*)d_in[3];
    const float* weight = (const float*)d_in[4];
    const float* bias   = (const float*)d_in[5];
    float*       out    = (float*)d_out;

    const int n_edges = in_sizes[2];
    const int n_feat  = in_sizes[0];   // N*64 floats

    // workspace layout (ints); all vector bases 16B-aligned
    int*   counts   = (int*)d_ws;              // NSCAN
    int*   offsets  = counts   + NSCAN;        // NSCAN  (offsets[N] valid)
    int*   partials = offsets  + NSCAN;        // 64
    int*   rank     = partials + 64;           // n_edges
    int*   edge_src = rank     + n_edges;      // n_edges
    uint4* hsb      = (uint4*)(edge_src + n_edges);   // N*64 fp16 = N*8 uint4

    // zero the histogram (ws is poisoned; everything else is fully rewritten)
    hipMemsetAsync(counts, 0, NSCAN * sizeof(int), stream);

    int n8 = n_feat / 8;   // 800000
    convert_fp16<<<(n8 + 255) / 256, 256, 0, stream>>>(h_src, hsb, n8);

    int nbE4 = ((n_edges + 3) / 4 + 255) / 256;
    edge_hist<<<nbE4, 256, 0, stream>>>(dst, counts, rank, n_edges);
    scan_block<<<NB_SCAN, SCAN_BS, 0, stream>>>(counts, offsets, partials);
    scan_add<<<NB_SCAN, SCAN_BS, 0, stream>>>(offsets, partials);
    edge_fill<<<nbE4, 256, 0, stream>>>(src, dst, rank, offsets, edge_src, n_edges);

    sage_fused<<<(N_NODES_C + 63) / 64, 256, 0, stream>>>(
        hsb, h_dst, offsets, edge_src, weight, bias, out, N_NODES_C);
}

// Round 10
// 207.097 us; speedup vs baseline: 1.0168x; 1.0168x over previous
//
#include <hip/hip_runtime.h>
#include <hip/hip_bf16.h>
#include <hip/hip_fp16.h>

#define N_NODES_C 100000
#define NSCAN     102400      // N padded to 25 * 4096 for the scan
#define SCAN_BS   1024        // threads per scan block (4 elems each -> 4096/block)
#define NB_SCAN   (NSCAN / (SCAN_BS * 4))   // 25 blocks

typedef unsigned u32x4 __attribute__((ext_vector_type(4)));

// ---------------------------------------------------------------------------
// fp16 helpers: h_src stored as packed fp16 (uint = 2 halves)
// ---------------------------------------------------------------------------
union U2H { unsigned u; __half2 h; };

__device__ __forceinline__ __half2 addp(__half2 a, unsigned u)
{
    U2H c; c.u = u;
    return __hadd2(a, c.h);
}

// h_src f32 -> packed fp16 copy (8 floats per thread)
__global__ __launch_bounds__(256) void convert_fp16(
    const float* __restrict__ x, uint4* __restrict__ y, int n8)
{
    int i = blockIdx.x * 256 + threadIdx.x;
    if (i >= n8) return;
    const float4* x4 = reinterpret_cast<const float4*>(x);
    float4 a = x4[i * 2 + 0];
    float4 b = x4[i * 2 + 1];
    U2H c0, c1, c2, c3;
    c0.h = __floats2half2_rn(a.x, a.y);
    c1.h = __floats2half2_rn(a.z, a.w);
    c2.h = __floats2half2_rn(b.x, b.y);
    c3.h = __floats2half2_rn(b.z, b.w);
    uint4 o;
    o.x = c0.u; o.y = c1.u; o.z = c2.u; o.w = c3.u;
    y[i] = o;
}

// ---------------------------------------------------------------------------
// CSR build: histogram(+rank) -> block scan -> scan_add(inline partials) -> fill
// ---------------------------------------------------------------------------
__global__ __launch_bounds__(256) void edge_hist(
    const int* __restrict__ dst, int* __restrict__ counts,
    int* __restrict__ rank, int n_edges)
{
    int i = blockIdx.x * 256 + threadIdx.x;
    int b4 = i * 4;
    if (b4 + 3 < n_edges) {
        int4 d = reinterpret_cast<const int4*>(dst)[i];
        int4 rk;
        rk.x = atomicAdd(&counts[d.x], 1);
        rk.y = atomicAdd(&counts[d.y], 1);
        rk.z = atomicAdd(&counts[d.z], 1);
        rk.w = atomicAdd(&counts[d.w], 1);
        reinterpret_cast<int4*>(rank)[i] = rk;
    } else {
        for (int e = b4; e < n_edges; ++e)
            rank[e] = atomicAdd(&counts[dst[e]], 1);
    }
}

__global__ __launch_bounds__(SCAN_BS) void scan_block(
    const int* __restrict__ counts, int* __restrict__ offsets,
    int* __restrict__ partials)
{
    __shared__ int sd[2][SCAN_BS];
    int t = threadIdx.x, b = blockIdx.x;
    int4 c = reinterpret_cast<const int4*>(counts)[b * SCAN_BS + t];
    int tot = c.x + c.y + c.z + c.w;
    sd[0][t] = tot;
    __syncthreads();
    int pin = 0;
    #pragma unroll
    for (int off = 1; off < SCAN_BS; off <<= 1) {
        int v = sd[pin][t];
        if (t >= off) v += sd[pin][t - off];
        sd[pin ^ 1][t] = v;
        pin ^= 1;
        __syncthreads();
    }
    int incl = sd[pin][t];      // inclusive scan of per-thread sums
    int excl = incl - tot;
    int4 o;
    o.x = excl;
    o.y = excl + c.x;
    o.z = excl + c.x + c.y;
    o.w = excl + c.x + c.y + c.z;
    reinterpret_cast<int4*>(offsets)[b * SCAN_BS + t] = o;
    if (t == SCAN_BS - 1) partials[b] = incl;
}

// one block per scan_block tile; thread 0 sums the (<=24) preceding partials
__global__ __launch_bounds__(SCAN_BS) void scan_add(
    int* __restrict__ offsets, const int* __restrict__ partials)
{
    __shared__ int base_s;
    int b = blockIdx.x;
    if (threadIdx.x == 0) {
        int s = 0;
        for (int i = 0; i < b; ++i) s += partials[i];
        base_s = s;
    }
    __syncthreads();
    int i = b * SCAN_BS + threadIdx.x;
    int4 v = reinterpret_cast<int4*>(offsets)[i];
    v.x += base_s; v.y += base_s; v.z += base_s; v.w += base_s;
    reinterpret_cast<int4*>(offsets)[i] = v;
}

__global__ __launch_bounds__(256) void edge_fill(
    const int* __restrict__ src, const int* __restrict__ dst,
    const int* __restrict__ rank, const int* __restrict__ offsets,
    int* __restrict__ edge_src, int n_edges)
{
    int i = blockIdx.x * 256 + threadIdx.x;
    int b4 = i * 4;
    if (b4 + 3 < n_edges) {
        int4 s  = reinterpret_cast<const int4*>(src)[i];
        int4 d  = reinterpret_cast<const int4*>(dst)[i];
        int4 rk = reinterpret_cast<const int4*>(rank)[i];
        edge_src[offsets[d.x] + rk.x] = s.x;
        edge_src[offsets[d.y] + rk.y] = s.y;
        edge_src[offsets[d.z] + rk.z] = s.z;
        edge_src[offsets[d.w] + rk.w] = s.w;
    } else {
        for (int e = b4; e < n_edges; ++e)
            edge_src[offsets[dst[e]] + rank[e]] = src[e];
    }
}

// ---------------------------------------------------------------------------
// Fused gather-mean + GEMM.
// Block: 256 threads, 64 nodes. LDS: X tile only (32KB, swizzled float4).
// Gather: 4 threads/node; per edge each lane covers 2 uint4 fp16 chunks
// (j and j+4, 64B apart). 4-edge unroll; the 8 loads + vmcnt(0) live in
// ONE asm blob whose outputs are ALL EARLY-CLOBBER ("=&v") -> the register
// allocator must give 8 distinct concurrently-live dest quads, disjoint
// from the 4 address pairs (R8's plain "=v" allowed dest/addr overlap ->
// async VMEM writeback corrupted a pending address -> abort). This forces
// R2's 8-deep MLP, which no C-level formulation achieved (VGPR stuck 40-60,
// loads serialized, R5-R9).
// W streams from global in the GEMM loop (L1-resident, 16-lane dedup).
// ---------------------------------------------------------------------------
__global__ __launch_bounds__(256) void sage_fused(
    const uint4* __restrict__ hsb,      // packed fp16 h_src [N][8] uint4
    const float* __restrict__ h_dst,
    const int*   __restrict__ offsets,
    const int*   __restrict__ edge_src,
    const float* __restrict__ weight,   // [64][128] row-major
    const float* __restrict__ bias,     // [64]
    float*       __restrict__ out,      // [N][64]
    int n_nodes)
{
    __shared__ float4 x4[64 * 32];   // x4[r][c] at r*32 + ((c + r) & 31)

    const int t    = threadIdx.x;
    const int base = blockIdx.x * 64;

    // stage h_dst (cols 0..15): 4 float4 per thread
    #pragma unroll
    for (int q = 0; q < 4; ++q) {
        int idx = t + q * 256;        // 0..1023
        int r   = idx >> 4;
        int k4  = idx & 15;
        int g   = base + r;
        float4 xv = make_float4(0.f, 0.f, 0.f, 0.f);
        if (g < n_nodes)
            xv = reinterpret_cast<const float4*>(h_dst)[(size_t)g * 16 + k4];
        x4[r * 32 + ((k4 + r) & 31)] = xv;
    }

    // gather neighbor mean (cols 16..31): 4 threads/node, 4-edge unroll,
    // 8 concurrent 16B gathers per lane forced by early-clobber asm
    {
        const int j = t & 3;          // uint4 chunk pair: j and j+4
        const int r = t >> 2;         // node within tile (0..63)
        const int g = base + r;
        __half2 accA[4], accB[4];     // features [8j..8j+8) and [8(j+4)..)
        const __half2 z = __floats2half2_rn(0.f, 0.f);
        #pragma unroll
        for (int q = 0; q < 4; ++q) { accA[q] = z; accB[q] = z; }
        float invd = 0.f;
        if (g < n_nodes) {
            int e0 = offsets[g];
            int e1 = offsets[g + 1];
            int e  = e0;
            for (; e + 4 <= e1; e += 4) {
                int s0 = edge_src[e + 0];
                int s1 = edge_src[e + 1];
                int s2 = edge_src[e + 2];
                int s3 = edge_src[e + 3];
                const uint4* a0 = hsb + (size_t)s0 * 8 + j;
                const uint4* a1 = hsb + (size_t)s1 * 8 + j;
                const uint4* a2 = hsb + (size_t)s2 * 8 + j;
                const uint4* a3 = hsb + (size_t)s3 * 8 + j;
                u32x4 p0, p1, p2, p3, q0, q1, q2, q3;
                asm volatile(
                    "global_load_dwordx4 %0, %8, off\n\t"
                    "global_load_dwordx4 %1, %9, off\n\t"
                    "global_load_dwordx4 %2, %10, off\n\t"
                    "global_load_dwordx4 %3, %11, off\n\t"
                    "global_load_dwordx4 %4, %8, off offset:64\n\t"
                    "global_load_dwordx4 %5, %9, off offset:64\n\t"
                    "global_load_dwordx4 %6, %10, off offset:64\n\t"
                    "global_load_dwordx4 %7, %11, off offset:64\n\t"
                    "s_waitcnt vmcnt(0)"
                    : "=&v"(p0), "=&v"(p1), "=&v"(p2), "=&v"(p3),
                      "=&v"(q0), "=&v"(q1), "=&v"(q2), "=&v"(q3)
                    : "v"(a0), "v"(a1), "v"(a2), "v"(a3));
                accA[0] = addp(accA[0], p0.x); accA[1] = addp(accA[1], p0.y);
                accA[2] = addp(accA[2], p0.z); accA[3] = addp(accA[3], p0.w);
                accA[0] = addp(accA[0], p1.x); accA[1] = addp(accA[1], p1.y);
                accA[2] = addp(accA[2], p1.z); accA[3] = addp(accA[3], p1.w);
                accA[0] = addp(accA[0], p2.x); accA[1] = addp(accA[1], p2.y);
                accA[2] = addp(accA[2], p2.z); accA[3] = addp(accA[3], p2.w);
                accA[0] = addp(accA[0], p3.x); accA[1] = addp(accA[1], p3.y);
                accA[2] = addp(accA[2], p3.z); accA[3] = addp(accA[3], p3.w);
                accB[0] = addp(accB[0], q0.x); accB[1] = addp(accB[1], q0.y);
                accB[2] = addp(accB[2], q0.z); accB[3] = addp(accB[3], q0.w);
                accB[0] = addp(accB[0], q1.x); accB[1] = addp(accB[1], q1.y);
                accB[2] = addp(accB[2], q1.z); accB[3] = addp(accB[3], q1.w);
                accB[0] = addp(accB[0], q2.x); accB[1] = addp(accB[1], q2.y);
                accB[2] = addp(accB[2], q2.z); accB[3] = addp(accB[3], q2.w);
                accB[0] = addp(accB[0], q3.x); accB[1] = addp(accB[1], q3.y);
                accB[2] = addp(accB[2], q3.z); accB[3] = addp(accB[3], q3.w);
            }
            for (; e < e1; ++e) {
                int s = edge_src[e];
                uint4 p = hsb[(size_t)s * 8 + j];
                uint4 q = hsb[(size_t)s * 8 + j + 4];
                accA[0] = addp(accA[0], p.x); accA[1] = addp(accA[1], p.y);
                accA[2] = addp(accA[2], p.z); accA[3] = addp(accA[3], p.w);
                accB[0] = addp(accB[0], q.x); accB[1] = addp(accB[1], q.y);
                accB[2] = addp(accB[2], q.z); accB[3] = addp(accB[3], q.w);
            }
            int degv = e1 - e0;
            invd = 1.0f / (float)(degv > 1 ? degv : 1);
        }
        // chunk j  -> float4 cols 16+2j, 17+2j ; chunk j+4 -> 24+2j, 25+2j
        float4 w0 = make_float4(__low2float(accA[0]) * invd,
                                __high2float(accA[0]) * invd,
                                __low2float(accA[1]) * invd,
                                __high2float(accA[1]) * invd);
        float4 w1 = make_float4(__low2float(accA[2]) * invd,
                                __high2float(accA[2]) * invd,
                                __low2float(accA[3]) * invd,
                                __high2float(accA[3]) * invd);
        float4 w2 = make_float4(__low2float(accB[0]) * invd,
                                __high2float(accB[0]) * invd,
                                __low2float(accB[1]) * invd,
                                __high2float(accB[1]) * invd);
        float4 w3 = make_float4(__low2float(accB[2]) * invd,
                                __high2float(accB[2]) * invd,
                                __low2float(accB[3]) * invd,
                                __high2float(accB[3]) * invd);
        x4[r * 32 + (((16 + 2 * j) + r) & 31)] = w0;
        x4[r * 32 + (((17 + 2 * j) + r) & 31)] = w1;
        x4[r * 32 + (((24 + 2 * j) + r) & 31)] = w2;
        x4[r * 32 + (((25 + 2 * j) + r) & 31)] = w3;
    }
    __syncthreads();

    // GEMM: thread tile = 4 nodes x 4 outs; W streamed from global (L1)
    const int m  = t & 15;    // out-group: o0 = 4m
    const int r0 = t >> 4;    // node base: rows r0 + 16*i
    const int o0 = m * 4;

    const float4* w4g = reinterpret_cast<const float4*>(weight);
    float4 bv = reinterpret_cast<const float4*>(bias)[m];

    float acc[4][4];
    #pragma unroll
    for (int i = 0; i < 4; ++i) {
        acc[i][0] = bv.x; acc[i][1] = bv.y; acc[i][2] = bv.z; acc[i][3] = bv.w;
    }

    #pragma unroll 4
    for (int k4 = 0; k4 < 32; ++k4) {
        float4 wv[4];
        #pragma unroll
        for (int jj = 0; jj < 4; ++jj)
            wv[jj] = w4g[(o0 + jj) * 32 + k4];
        #pragma unroll
        for (int i = 0; i < 4; ++i) {
            int r = r0 + 16 * i;
            float4 xv = x4[r * 32 + ((k4 + r) & 31)];
            #pragma unroll
            for (int jj = 0; jj < 4; ++jj) {
                acc[i][jj] += xv.x * wv[jj].x + xv.y * wv[jj].y
                            + xv.z * wv[jj].z + xv.w * wv[jj].w;
            }
        }
    }

    #pragma unroll
    for (int i = 0; i < 4; ++i) {
        int g = base + r0 + 16 * i;
        if (g < n_nodes) {
            float4 ov = make_float4(acc[i][0], acc[i][1], acc[i][2], acc[i][3]);
            reinterpret_cast<float4*>(out)[(size_t)g * 16 + m] = ov;
        }
    }
}

// ---------------------------------------------------------------------------
extern "C" void kernel_launch(void* const* d_in, const int* in_sizes, int n_in,
                              void* d_out, int out_size, void* d_ws, size_t ws_size,
                              hipStream_t stream)
{
    const float* h_src  = (const float*)d_in[0];
    const float* h_dst  = (const float*)d_in[1];
    const int*   src    = (const int*)d_in[2];
    const int*   dst    = (const int*)d_in[3];
    const float* weight = (const float*)d_in[4];
    const float* bias   = (const float*)d_in[5];
    float*       out    = (float*)d_out;

    const int n_edges = in_sizes[2];
    const int n_feat  = in_sizes[0];   // N*64 floats

    // workspace layout (ints); all vector bases 16B-aligned
    int*   counts   = (int*)d_ws;              // NSCAN
    int*   offsets  = counts   + NSCAN;        // NSCAN  (offsets[N] valid)
    int*   partials = offsets  + NSCAN;        // 64
    int*   rank     = partials + 64;           // n_edges
    int*   edge_src = rank     + n_edges;      // n_edges
    uint4* hsb      = (uint4*)(edge_src + n_edges);   // N*64 fp16 = N*8 uint4

    // zero the histogram (ws is poisoned; everything else is fully rewritten)
    hipMemsetAsync(counts, 0, NSCAN * sizeof(int), stream);

    int n8 = n_feat / 8;   // 800000
    convert_fp16<<<(n8 + 255) / 256, 256, 0, stream>>>(h_src, hsb, n8);

    int nbE4 = ((n_edges + 3) / 4 + 255) / 256;
    edge_hist<<<nbE4, 256, 0, stream>>>(dst, counts, rank, n_edges);
    scan_block<<<NB_SCAN, SCAN_BS, 0, stream>>>(counts, offsets, partials);
    scan_add<<<NB_SCAN, SCAN_BS, 0, stream>>>(offsets, partials);
    edge_fill<<<nbE4, 256, 0, stream>>>(src, dst, rank, offsets, edge_src, n_edges);

    sage_fused<<<(N_NODES_C + 63) / 64, 256, 0, stream>>>(
        hsb, h_dst, offsets, edge_src, weight, bias, out, N_NODES_C);
}

// Round 11
// 201.129 us; speedup vs baseline: 1.0470x; 1.0297x over previous
//
#include <hip/hip_runtime.h>
#include <hip/hip_bf16.h>
#include <hip/hip_fp16.h>

#define N_NODES_C 100000
#define NSCAN     102400      // N padded to 25 * 4096 for the scan
#define SCAN_BS   1024        // threads per scan block (4 elems each -> 4096/block)
#define NB_SCAN   (NSCAN / (SCAN_BS * 4))   // 25 blocks

typedef unsigned u32x4 __attribute__((ext_vector_type(4)));

// ---------------------------------------------------------------------------
// fp16 helpers: h_src stored as packed fp16 (uint = 2 halves)
// ---------------------------------------------------------------------------
union U2H { unsigned u; __half2 h; };

__device__ __forceinline__ __half2 addp(__half2 a, unsigned u)
{
    U2H c; c.u = u;
    return __hadd2(a, c.h);
}

// h_src f32 -> packed fp16 copy; row N_NODES_C is written as zeros (pad row)
__global__ __launch_bounds__(256) void convert_fp16(
    const float* __restrict__ x, uint4* __restrict__ y, int n8)
{
    int i = blockIdx.x * 256 + threadIdx.x;
    if (i >= n8 + 8) return;
    if (i >= n8) { y[i] = make_uint4(0u, 0u, 0u, 0u); return; }
    const float4* x4 = reinterpret_cast<const float4*>(x);
    float4 a = x4[i * 2 + 0];
    float4 b = x4[i * 2 + 1];
    U2H c0, c1, c2, c3;
    c0.h = __floats2half2_rn(a.x, a.y);
    c1.h = __floats2half2_rn(a.z, a.w);
    c2.h = __floats2half2_rn(b.x, b.y);
    c3.h = __floats2half2_rn(b.z, b.w);
    uint4 o;
    o.x = c0.u; o.y = c1.u; o.z = c2.u; o.w = c3.u;
    y[i] = o;
}

// ---------------------------------------------------------------------------
// CSR build (padded-to-4 segments):
// histogram(+rank) -> block scan of PADDED counts -> scan_add (+pad fill) -> fill
// ---------------------------------------------------------------------------
__global__ __launch_bounds__(256) void edge_hist(
    const int* __restrict__ dst, int* __restrict__ counts,
    int* __restrict__ rank, int n_edges)
{
    int i = blockIdx.x * 256 + threadIdx.x;
    int b4 = i * 4;
    if (b4 + 3 < n_edges) {
        int4 d = reinterpret_cast<const int4*>(dst)[i];
        int4 rk;
        rk.x = atomicAdd(&counts[d.x], 1);
        rk.y = atomicAdd(&counts[d.y], 1);
        rk.z = atomicAdd(&counts[d.z], 1);
        rk.w = atomicAdd(&counts[d.w], 1);
        reinterpret_cast<int4*>(rank)[i] = rk;
    } else {
        for (int e = b4; e < n_edges; ++e)
            rank[e] = atomicAdd(&counts[dst[e]], 1);
    }
}

__global__ __launch_bounds__(SCAN_BS) void scan_block(
    const int* __restrict__ counts, int* __restrict__ offsets,
    int* __restrict__ partials)
{
    __shared__ int sd[2][SCAN_BS];
    int t = threadIdx.x, b = blockIdx.x;
    int4 c = reinterpret_cast<const int4*>(counts)[b * SCAN_BS + t];
    int q0 = (c.x + 3) & ~3;
    int q1 = (c.y + 3) & ~3;
    int q2 = (c.z + 3) & ~3;
    int q3 = (c.w + 3) & ~3;
    int tot = q0 + q1 + q2 + q3;
    sd[0][t] = tot;
    __syncthreads();
    int pin = 0;
    #pragma unroll
    for (int off = 1; off < SCAN_BS; off <<= 1) {
        int v = sd[pin][t];
        if (t >= off) v += sd[pin][t - off];
        sd[pin ^ 1][t] = v;
        pin ^= 1;
        __syncthreads();
    }
    int incl = sd[pin][t];      // inclusive scan of per-thread padded sums
    int excl = incl - tot;
    int4 o;
    o.x = excl;
    o.y = excl + q0;
    o.z = excl + q0 + q1;
    o.w = excl + q0 + q1 + q2;
    reinterpret_cast<int4*>(offsets)[b * SCAN_BS + t] = o;
    if (t == SCAN_BS - 1) partials[b] = incl;
}

// add block bases; also fill each node's pad slots with the dummy index N
__global__ __launch_bounds__(SCAN_BS) void scan_add(
    int* __restrict__ offsets, const int* __restrict__ partials,
    const int* __restrict__ counts, int* __restrict__ edge_src)
{
    __shared__ int base_s;
    int b = blockIdx.x;
    if (threadIdx.x == 0) {
        int s = 0;
        for (int i = 0; i < b; ++i) s += partials[i];
        base_s = s;
    }
    __syncthreads();
    int i = b * SCAN_BS + threadIdx.x;
    int4 v = reinterpret_cast<int4*>(offsets)[i];
    v.x += base_s; v.y += base_s; v.z += base_s; v.w += base_s;
    reinterpret_cast<int4*>(offsets)[i] = v;
    int4 c = reinterpret_cast<const int4*>(counts)[i];
    int s, ep;
    s = v.x + c.x; ep = v.x + ((c.x + 3) & ~3); for (; s < ep; ++s) edge_src[s] = N_NODES_C;
    s = v.y + c.y; ep = v.y + ((c.y + 3) & ~3); for (; s < ep; ++s) edge_src[s] = N_NODES_C;
    s = v.z + c.z; ep = v.z + ((c.z + 3) & ~3); for (; s < ep; ++s) edge_src[s] = N_NODES_C;
    s = v.w + c.w; ep = v.w + ((c.w + 3) & ~3); for (; s < ep; ++s) edge_src[s] = N_NODES_C;
}

__global__ __launch_bounds__(256) void edge_fill(
    const int* __restrict__ src, const int* __restrict__ dst,
    const int* __restrict__ rank, const int* __restrict__ offsets,
    int* __restrict__ edge_src, int n_edges)
{
    int i = blockIdx.x * 256 + threadIdx.x;
    int b4 = i * 4;
    if (b4 + 3 < n_edges) {
        int4 s  = reinterpret_cast<const int4*>(src)[i];
        int4 d  = reinterpret_cast<const int4*>(dst)[i];
        int4 rk = reinterpret_cast<const int4*>(rank)[i];
        edge_src[offsets[d.x] + rk.x] = s.x;
        edge_src[offsets[d.y] + rk.y] = s.y;
        edge_src[offsets[d.z] + rk.z] = s.z;
        edge_src[offsets[d.w] + rk.w] = s.w;
    } else {
        for (int e = b4; e < n_edges; ++e)
            edge_src[offsets[dst[e]] + rank[e]] = src[e];
    }
}

// ---------------------------------------------------------------------------
// Fused gather-mean + GEMM with a 2-deep cross-group software pipeline.
// Per 4-lane group, per 4-edge "group": indices via ONE dwordx4 (contiguous,
// padded CSR), rows via 8 dwordx4 into double-buffered quad sets pA/pB.
// Steady state (all asm, counted waits -- never vmcnt(0)):
//   IDX(next) ; ROWS(cur) ; vmcnt(9) [prev rows done, cur 8 + idx in flight]
//   consume prev ; vmcnt(8) [idx done] ; compute next addrs
// Wave-uniform trip count (shfl-max) + zero pad-row keeps the instruction
// stream divergence-free so the per-wave vmcnt discipline holds.
// ---------------------------------------------------------------------------

#define GL_ROWS(p0,p1,p2,p3,p4,p5,p6,p7) \
    asm volatile( \
        "global_load_dwordx4 %0, %8, off\n\t" \
        "global_load_dwordx4 %1, %9, off\n\t" \
        "global_load_dwordx4 %2, %10, off\n\t" \
        "global_load_dwordx4 %3, %11, off\n\t" \
        "global_load_dwordx4 %4, %8, off offset:64\n\t" \
        "global_load_dwordx4 %5, %9, off offset:64\n\t" \
        "global_load_dwordx4 %6, %10, off offset:64\n\t" \
        "global_load_dwordx4 %7, %11, off offset:64" \
        : "=&v"(p0), "=&v"(p1), "=&v"(p2), "=&v"(p3), \
          "=&v"(p4), "=&v"(p5), "=&v"(p6), "=&v"(p7) \
        : "v"(a0), "v"(a1), "v"(a2), "v"(a3))

#define GL_IDX() \
    asm volatile("global_load_dwordx4 %0, %1, off" \
        : "=&v"(idxQ) : "v"((const int*)(edge_src + e)))

#define WAITN(n,p0,p1,p2,p3,p4,p5,p6,p7) \
    asm volatile("s_waitcnt vmcnt(" #n ")" \
        : "+v"(p0), "+v"(p1), "+v"(p2), "+v"(p3), \
          "+v"(p4), "+v"(p5), "+v"(p6), "+v"(p7))

#define WAITI(n) asm volatile("s_waitcnt vmcnt(" #n ")" : "+v"(idxQ))

#define ADDR(TGT) do { \
    int s0_ = (int)idxQ[0], s1_ = (int)idxQ[1], s2_ = (int)idxQ[2], s3_ = (int)idxQ[3]; \
    bool ok_ = (TGT) < nit; \
    a0 = ok_ ? (hsb + ((size_t)s0_ * 8 + j)) : zrow; \
    a1 = ok_ ? (hsb + ((size_t)s1_ * 8 + j)) : zrow; \
    a2 = ok_ ? (hsb + ((size_t)s2_ * 8 + j)) : zrow; \
    a3 = ok_ ? (hsb + ((size_t)s3_ * 8 + j)) : zrow; \
} while (0)

#define CONS(p0,p1,p2,p3,p4,p5,p6,p7) do { \
    accA[0] = addp(accA[0], p0[0]); accA[1] = addp(accA[1], p0[1]); \
    accA[2] = addp(accA[2], p0[2]); accA[3] = addp(accA[3], p0[3]); \
    accA[0] = addp(accA[0], p1[0]); accA[1] = addp(accA[1], p1[1]); \
    accA[2] = addp(accA[2], p1[2]); accA[3] = addp(accA[3], p1[3]); \
    accA[0] = addp(accA[0], p2[0]); accA[1] = addp(accA[1], p2[1]); \
    accA[2] = addp(accA[2], p2[2]); accA[3] = addp(accA[3], p2[3]); \
    accA[0] = addp(accA[0], p3[0]); accA[1] = addp(accA[1], p3[1]); \
    accA[2] = addp(accA[2], p3[2]); accA[3] = addp(accA[3], p3[3]); \
    accB[0] = addp(accB[0], p4[0]); accB[1] = addp(accB[1], p4[1]); \
    accB[2] = addp(accB[2], p4[2]); accB[3] = addp(accB[3], p4[3]); \
    accB[0] = addp(accB[0], p5[0]); accB[1] = addp(accB[1], p5[1]); \
    accB[2] = addp(accB[2], p5[2]); accB[3] = addp(accB[3], p5[3]); \
    accB[0] = addp(accB[0], p6[0]); accB[1] = addp(accB[1], p6[1]); \
    accB[2] = addp(accB[2], p6[2]); accB[3] = addp(accB[3], p6[3]); \
    accB[0] = addp(accB[0], p7[0]); accB[1] = addp(accB[1], p7[1]); \
    accB[2] = addp(accB[2], p7[2]); accB[3] = addp(accB[3], p7[3]); \
} while (0)

__global__ __launch_bounds__(256) void sage_fused(
    const uint4* __restrict__ hsb,      // packed fp16 h_src [(N+1)][8] uint4
    const float* __restrict__ h_dst,
    const int*   __restrict__ offsets,  // padded CSR offsets
    const int*   __restrict__ counts,   // raw degrees
    const int*   __restrict__ edge_src, // padded edge lists
    const float* __restrict__ weight,   // [64][128] row-major
    const float* __restrict__ bias,     // [64]
    float*       __restrict__ out,      // [N][64]
    int n_nodes)
{
    __shared__ float4 x4[64 * 32];   // x4[r][c] at r*32 + ((c + r) & 31)

    const int t    = threadIdx.x;
    const int base = blockIdx.x * 64;

    // stage h_dst (cols 0..15): 4 float4 per thread
    #pragma unroll
    for (int q = 0; q < 4; ++q) {
        int idx = t + q * 256;        // 0..1023
        int r   = idx >> 4;
        int k4  = idx & 15;
        int g   = base + r;
        float4 xv = make_float4(0.f, 0.f, 0.f, 0.f);
        if (g < n_nodes)
            xv = reinterpret_cast<const float4*>(h_dst)[(size_t)g * 16 + k4];
        x4[r * 32 + ((k4 + r) & 31)] = xv;
    }

    // gather neighbor mean (cols 16..31)
    {
        const int j = t & 3;          // uint4 chunk pair: j and j+4
        const int r = t >> 2;         // node within tile (0..63)
        const int g = base + r;       // < NSCAN always; may be >= n_nodes (deg 0)
        __half2 accA[4], accB[4];
        const __half2 z = __floats2half2_rn(0.f, 0.f);
        #pragma unroll
        for (int q = 0; q < 4; ++q) { accA[q] = z; accB[q] = z; }

        int e0  = offsets[g];
        int e1  = offsets[g + 1];
        int nit = (e1 - e0) >> 2;     // padded -> exact
        int deg = counts[g];

        int nmax = nit;               // wave-uniform trip count
        #pragma unroll
        for (int off = 4; off < 64; off <<= 1) {
            int o = __shfl_xor(nmax, off, 64);
            nmax = nmax > o ? nmax : o;
        }

        const uint4* zrow = hsb + ((size_t)N_NODES_C * 8 + j);
        const uint4* a0 = zrow, *a1 = zrow, *a2 = zrow, *a3 = zrow;
        u32x4 pA0, pA1, pA2, pA3, pA4, pA5, pA6, pA7;
        u32x4 pB0, pB1, pB2, pB3, pB4, pB5, pB6, pB7;
        u32x4 idxQ;
        int e = e0;

        if (nmax > 0) {
            GL_IDX(); e += 4;
            WAITI(0);
            ADDR(0);
            if (nmax == 1) {
                GL_ROWS(pA0,pA1,pA2,pA3,pA4,pA5,pA6,pA7);
                WAITN(0, pA0,pA1,pA2,pA3,pA4,pA5,pA6,pA7);
                CONS(pA0,pA1,pA2,pA3,pA4,pA5,pA6,pA7);
            } else {
                GL_IDX(); e += 4;                         // idx for group 1
                GL_ROWS(pA0,pA1,pA2,pA3,pA4,pA5,pA6,pA7); // rows group 0
                WAITI(8);                                 // idx1 ready, rows in flight
                ADDR(1);
                int it = 1;
                for (; it + 1 < nmax; it += 2) {
                    GL_IDX(); e += 4;
                    GL_ROWS(pB0,pB1,pB2,pB3,pB4,pB5,pB6,pB7);
                    WAITN(9, pA0,pA1,pA2,pA3,pA4,pA5,pA6,pA7);
                    CONS(pA0,pA1,pA2,pA3,pA4,pA5,pA6,pA7);
                    WAITI(8);
                    ADDR(it + 1);
                    GL_IDX(); e += 4;
                    GL_ROWS(pA0,pA1,pA2,pA3,pA4,pA5,pA6,pA7);
                    WAITN(9, pB0,pB1,pB2,pB3,pB4,pB5,pB6,pB7);
                    CONS(pB0,pB1,pB2,pB3,pB4,pB5,pB6,pB7);
                    WAITI(8);
                    ADDR(it + 2);
                }
                if (it < nmax) {
                    GL_ROWS(pB0,pB1,pB2,pB3,pB4,pB5,pB6,pB7);
                    WAITN(8, pA0,pA1,pA2,pA3,pA4,pA5,pA6,pA7);
                    CONS(pA0,pA1,pA2,pA3,pA4,pA5,pA6,pA7);
                    WAITN(0, pB0,pB1,pB2,pB3,pB4,pB5,pB6,pB7);
                    CONS(pB0,pB1,pB2,pB3,pB4,pB5,pB6,pB7);
                } else {
                    WAITN(0, pA0,pA1,pA2,pA3,pA4,pA5,pA6,pA7);
                    CONS(pA0,pA1,pA2,pA3,pA4,pA5,pA6,pA7);
                }
            }
        }

        float invd = 1.0f / (float)(deg > 1 ? deg : 1);
        float4 w0 = make_float4(__low2float(accA[0]) * invd,
                                __high2float(accA[0]) * invd,
                                __low2float(accA[1]) * invd,
                                __high2float(accA[1]) * invd);
        float4 w1 = make_float4(__low2float(accA[2]) * invd,
                                __high2float(accA[2]) * invd,
                                __low2float(accA[3]) * invd,
                                __high2float(accA[3]) * invd);
        float4 w2 = make_float4(__low2float(accB[0]) * invd,
                                __high2float(accB[0]) * invd,
                                __low2float(accB[1]) * invd,
                                __high2float(accB[1]) * invd);
        float4 w3 = make_float4(__low2float(accB[2]) * invd,
                                __high2float(accB[2]) * invd,
                                __low2float(accB[3]) * invd,
                                __high2float(accB[3]) * invd);
        x4[r * 32 + (((16 + 2 * j) + r) & 31)] = w0;
        x4[r * 32 + (((17 + 2 * j) + r) & 31)] = w1;
        x4[r * 32 + (((24 + 2 * j) + r) & 31)] = w2;
        x4[r * 32 + (((25 + 2 * j) + r) & 31)] = w3;
    }
    __syncthreads();

    // GEMM: thread tile = 4 nodes x 4 outs; W streamed from global (L1)
    const int m  = t & 15;    // out-group: o0 = 4m
    const int r0 = t >> 4;    // node base: rows r0 + 16*i
    const int o0 = m * 4;

    const float4* w4g = reinterpret_cast<const float4*>(weight);
    float4 bv = reinterpret_cast<const float4*>(bias)[m];

    float acc[4][4];
    #pragma unroll
    for (int i = 0; i < 4; ++i) {
        acc[i][0] = bv.x; acc[i][1] = bv.y; acc[i][2] = bv.z; acc[i][3] = bv.w;
    }

    #pragma unroll 4
    for (int k4 = 0; k4 < 32; ++k4) {
        float4 wv[4];
        #pragma unroll
        for (int jj = 0; jj < 4; ++jj)
            wv[jj] = w4g[(o0 + jj) * 32 + k4];
        #pragma unroll
        for (int i = 0; i < 4; ++i) {
            int r = r0 + 16 * i;
            float4 xv = x4[r * 32 + ((k4 + r) & 31)];
            #pragma unroll
            for (int jj = 0; jj < 4; ++jj) {
                acc[i][jj] += xv.x * wv[jj].x + xv.y * wv[jj].y
                            + xv.z * wv[jj].z + xv.w * wv[jj].w;
            }
        }
    }

    #pragma unroll
    for (int i = 0; i < 4; ++i) {
        int g = base + r0 + 16 * i;
        if (g < n_nodes) {
            float4 ov = make_float4(acc[i][0], acc[i][1], acc[i][2], acc[i][3]);
            reinterpret_cast<float4*>(out)[(size_t)g * 16 + m] = ov;
        }
    }
}

// ---------------------------------------------------------------------------
extern "C" void kernel_launch(void* const* d_in, const int* in_sizes, int n_in,
                              void* d_out, int out_size, void* d_ws, size_t ws_size,
                              hipStream_t stream)
{
    const float* h_src  = (const float*)d_in[0];
    const float* h_dst  = (const float*)d_in[1];
    const int*   src    = (const int*)d_in[2];
    const int*   dst    = (const int*)d_in[3];
    const float* weight = (const float*)d_in[4];
    const float* bias   = (const float*)d_in[5];
    float*       out    = (float*)d_out;

    const int n_edges = in_sizes[2];
    const int n_feat  = in_sizes[0];   // N*64 floats

    // workspace layout (ints); all vector bases 16B-aligned
    int*   counts   = (int*)d_ws;                         // NSCAN
    int*   offsets  = counts   + NSCAN;                   // NSCAN
    int*   partials = offsets  + NSCAN;                   // 64
    int*   rank     = partials + 64;                      // n_edges
    int*   edge_src = rank     + n_edges;                 // n_edges + 3*NSCAN + 64 (pads + prefetch slack)
    uint4* hsb      = (uint4*)(edge_src + n_edges + 3 * NSCAN + 64);  // (N+1)*8 uint4

    // zero the histogram (ws is poisoned; everything else is fully rewritten)
    hipMemsetAsync(counts, 0, NSCAN * sizeof(int), stream);

    int n8 = n_feat / 8;   // 800000
    convert_fp16<<<(n8 + 8 + 255) / 256, 256, 0, stream>>>(h_src, hsb, n8);

    int nbE4 = ((n_edges + 3) / 4 + 255) / 256;
    edge_hist<<<nbE4, 256, 0, stream>>>(dst, counts, rank, n_edges);
    scan_block<<<NB_SCAN, SCAN_BS, 0, stream>>>(counts, offsets, partials);
    scan_add<<<NB_SCAN, SCAN_BS, 0, stream>>>(offsets, partials, counts, edge_src);
    edge_fill<<<nbE4, 256, 0, stream>>>(src, dst, rank, offsets, edge_src, n_edges);

    sage_fused<<<(N_NODES_C + 63) / 64, 256, 0, stream>>>(
        hsb, h_dst, offsets, counts, edge_src, weight, bias, out, N_NODES_C);
}